// Round 18
// baseline (371.142 us; speedup 1.0000x reference)
//
#include <hip/hip_runtime.h>
#include <cstddef>
#include <cstdint>

#define D_MODEL 1024
#define NUM_HEADS 16
#define DK 64
#define D_FF 4096
#define SEQ 2048
#define BATCH 2
#define EPS 1e-5f

typedef unsigned short u16;
typedef __attribute__((ext_vector_type(8))) short bf16x8;
typedef __attribute__((ext_vector_type(8))) unsigned short us8;
typedef __attribute__((ext_vector_type(4))) unsigned short us4;
typedef __attribute__((ext_vector_type(4))) float f32x4;

#define SBAR() asm volatile("s_barrier" ::: "memory")

__device__ __forceinline__ u16 f2b(float f) {
    unsigned u = __float_as_uint(f);
    u += 0x7fffu + ((u >> 16) & 1u);          // round-to-nearest-even
    return (u16)(u >> 16);
}
__device__ __forceinline__ float b2f(u16 v) {
    return __uint_as_float((unsigned)v << 16);
}

__device__ __forceinline__ void gload16(const void* g, void* l) {
    __builtin_amdgcn_global_load_lds(
        (const __attribute__((address_space(1))) void*)g,
        (__attribute__((address_space(3))) void*)l, 16, 0, 0);
}

// ===========================================================================
// 256x256 8-wave GEMM, 4-phase/K-tile, counted vmcnt, LDS swizzle, setprio,
// bijective XCD swizzle.  (used for FF1: grid 256 = 1 block/CU, 8 waves)
// ===========================================================================
__device__ __forceinline__ void stage_half(
    const u16* __restrict__ g, int ld, long kbase, int h,
    u16* dst, int tid, int wid)
{
#pragma unroll
    for (int r = 0; r < 2; ++r) {
        const int ci  = r * 512 + tid;
        const int row = ci >> 2;
        const int wd  = ci & 3;
        const int f   = (row + (row >> 2)) & 3;
        const long src = (long)row * ld + kbase + (long)(h * 4 + (wd ^ f)) * 8;
        gload16(g + src, dst + (r * 512 + wid * 64) * 8);
    }
}

__device__ __forceinline__ bf16x8 frag64(const u16* base, int ks, int row, int g) {
    const int f = (row + (row >> 2)) & 3;
    return *(const bf16x8*)&base[ks * 8192 + row * 32 + ((g ^ f) * 8)];
}

template<int KTOT, bool RELU>
__global__ __launch_bounds__(512, 2) void gemm256(
    const u16* __restrict__ Abf, const u16* __restrict__ BT,
    const float* __restrict__ bias0, u16* __restrict__ C0,
    int ldc, int nx)
{
    constexpr int NT = KTOT / 64;
    __shared__ u16 lds[2][32768];

    const int tid = threadIdx.x;
    const int wid = tid >> 6, l = tid & 63;
    const int r16 = l & 15, g = l >> 4;
    const int wr = wid >> 2, wc = wid & 3;

    const int nwg = gridDim.x;
    const int q = nwg >> 3, rr = nwg & 7;
    const int xcd = blockIdx.x & 7, idx = blockIdx.x >> 3;
    const int wg = (xcd < rr ? xcd * (q + 1) : rr * (q + 1) + (xcd - rr) * q) + idx;
    const long bm = (long)(wg / nx) * 256;
    const long bn = (long)(wg % nx) * 256;

    const u16* Ag = Abf + bm * KTOT;
    const u16* Bg = BT + bn * KTOT;

    f32x4 acc[8][4];
#pragma unroll
    for (int i = 0; i < 8; ++i)
#pragma unroll
        for (int n = 0; n < 4; ++n)
            acc[i][n] = (f32x4){0.f, 0.f, 0.f, 0.f};

    stage_half(Ag, KTOT, 0, 0, &lds[0][0],     tid, wid);
    stage_half(Ag, KTOT, 0, 1, &lds[0][8192],  tid, wid);
    stage_half(Bg, KTOT, 0, 0, &lds[0][16384], tid, wid);
    stage_half(Bg, KTOT, 0, 1, &lds[0][24576], tid, wid);
    if (NT > 1) {
        stage_half(Ag, KTOT, 64, 0, &lds[1][0],     tid, wid);
        stage_half(Bg, KTOT, 64, 0, &lds[1][16384], tid, wid);
    }
    asm volatile("s_waitcnt vmcnt(4)" ::: "memory");
    SBAR();

    for (int t = 0; t < NT; ++t) {
        u16* cur = &lds[t & 1][0];
        u16* nxt = &lds[(t + 1) & 1][0];
        const long k1 = (long)(t + 1) * 64;
        const long k2 = (long)(t + 2) * 64;
        const bool s1 = (t + 1 < NT), s2 = (t + 2 < NT);

        bf16x8 a0[4], b0[4];
#pragma unroll
        for (int i = 0; i < 4; ++i) {
            a0[i] = frag64(cur,         0, wr * 128 + i * 16 + r16, g);
            b0[i] = frag64(cur + 16384, 0, wc * 64  + i * 16 + r16, g);
        }
        if (s1) stage_half(Ag, KTOT, k1, 1, nxt + 8192, tid, wid);
        SBAR();
        __builtin_amdgcn_s_setprio(1);
#pragma unroll
        for (int i = 0; i < 4; ++i)
#pragma unroll
            for (int n = 0; n < 4; ++n)
                acc[i][n] = __builtin_amdgcn_mfma_f32_16x16x32_bf16(
                    a0[i], b0[n], acc[i][n], 0, 0, 0);
        __builtin_amdgcn_s_setprio(0);
        SBAR();

        bf16x8 a1[4];
#pragma unroll
        for (int i = 0; i < 4; ++i)
            a1[i] = frag64(cur, 0, wr * 128 + (i + 4) * 16 + r16, g);
        if (s1) stage_half(Bg, KTOT, k1, 1, nxt + 24576, tid, wid);
        SBAR();
        __builtin_amdgcn_s_setprio(1);
#pragma unroll
        for (int i = 0; i < 4; ++i)
#pragma unroll
            for (int n = 0; n < 4; ++n)
                acc[i + 4][n] = __builtin_amdgcn_mfma_f32_16x16x32_bf16(
                    a1[i], b0[n], acc[i + 4][n], 0, 0, 0);
        __builtin_amdgcn_s_setprio(0);
        SBAR();

        bf16x8 a2[4], b1[4];
#pragma unroll
        for (int i = 0; i < 4; ++i) {
            a2[i] = frag64(cur,         1, wr * 128 + i * 16 + r16, g);
            b1[i] = frag64(cur + 16384, 1, wc * 64  + i * 16 + r16, g);
        }
        if (s2) stage_half(Ag, KTOT, k2, 0, cur, tid, wid);
        SBAR();
        __builtin_amdgcn_s_setprio(1);
#pragma unroll
        for (int i = 0; i < 4; ++i)
#pragma unroll
            for (int n = 0; n < 4; ++n)
                acc[i][n] = __builtin_amdgcn_mfma_f32_16x16x32_bf16(
                    a2[i], b1[n], acc[i][n], 0, 0, 0);
        __builtin_amdgcn_s_setprio(0);
        SBAR();

        bf16x8 a3[4];
#pragma unroll
        for (int i = 0; i < 4; ++i)
            a3[i] = frag64(cur, 1, wr * 128 + (i + 4) * 16 + r16, g);
        if (s2) stage_half(Bg, KTOT, k2, 0, cur + 16384, tid, wid);
        SBAR();
        __builtin_amdgcn_s_setprio(1);
#pragma unroll
        for (int i = 0; i < 4; ++i)
#pragma unroll
            for (int n = 0; n < 4; ++n)
                acc[i + 4][n] = __builtin_amdgcn_mfma_f32_16x16x32_bf16(
                    a3[i], b1[n], acc[i + 4][n], 0, 0, 0);
        __builtin_amdgcn_s_setprio(0);
        if (s2)      asm volatile("s_waitcnt vmcnt(4)" ::: "memory");
        else if (s1) asm volatile("s_waitcnt vmcnt(0)" ::: "memory");
        SBAR();
    }

    const long crow0 = bm + wr * 128 + g * 4;
    const long ccol0 = bn + wc * 64 + r16;
#pragma unroll
    for (int n = 0; n < 4; ++n) {
        const long col = ccol0 + n * 16;
        const float bv = bias0[col];
#pragma unroll
        for (int i = 0; i < 8; ++i)
#pragma unroll
            for (int j = 0; j < 4; ++j) {
                const long row = crow0 + i * 16 + j;
                float v = acc[i][n][j] + bv;
                if (RELU) v = fmaxf(v, 0.f);
                C0[row * (long)ldc + col] = f2b(v);
            }
    }
}

// ---------------------------------------------------------------------------
// 128x128-tile GEMM, BK=64, 512 threads (8 waves, wave tile 64x32),
// 3-buffer counted vmcnt(4).  96 KB LDS -> 1 block/CU (8 waves/CU).
// NSPLIT=3: QKV — cols [0,1024)->C0, [1024,2048)->C1, [2048,3072)->C2.
// ---------------------------------------------------------------------------
template<bool RELU, int NSPLIT>
__global__ __launch_bounds__(512) void gemm_w2(
    const u16* __restrict__ Abf, const u16* __restrict__ BT,
    const float* __restrict__ bias0, const float* __restrict__ bias1,
    const float* __restrict__ bias2,
    u16* __restrict__ C0, u16* __restrict__ C1, u16* __restrict__ C2,
    int lda, int ldb, int ldc, int K, int nx)
{
    constexpr int TILE = 16384;            // (128+128)*64 u16 = 32 KB
    __shared__ u16 sm[3][TILE];            // 96 KB

    const int tid = threadIdx.x;
    const int wid = tid >> 6, l = tid & 63;
    const int r16 = l & 15, g = l >> 4;
    const int wr = wid >> 2, wc = wid & 3;   // 2 x 4 wave grid; tile 64 x 32

    const int nwg = gridDim.x;
    const int q = nwg >> 3, rr = nwg & 7;
    const int xcd = blockIdx.x & 7, idx = blockIdx.x >> 3;
    const int wg = (xcd < rr ? xcd * (q + 1) : rr * (q + 1) + (xcd - rr) * q) + idx;
    const long bm = (long)(wg / nx) * 128;
    const long bn = (long)(wg % nx) * 128;

    f32x4 acc[4][2];
#pragma unroll
    for (int mi = 0; mi < 4; ++mi)
#pragma unroll
        for (int ni = 0; ni < 2; ++ni)
            acc[mi][ni] = (f32x4){0.f, 0.f, 0.f, 0.f};

    // staging offsets: A 128 rows x 8 slots (2 rounds), B same; slot^row&7
    long aOff[2], bOff[2];
#pragma unroll
    for (int r = 0; r < 2; ++r) {
        int c = r * 512 + tid;
        int row = c >> 3, sl = c & 7;
        aOff[r] = (long)(bm + row) * lda + (long)(sl ^ (row & 7)) * 8;
        bOff[r] = (long)(bn + row) * ldb + (long)(sl ^ (row & 7)) * 8;
    }

#define W2_STAGE(buf, koff)                                                   \
    {                                                                         \
        _Pragma("unroll")                                                     \
        for (int r = 0; r < 2; ++r)                                           \
            gload16(Abf + aOff[r] + (koff), &sm[buf][0] + (r * 512 + wid * 64) * 8); \
        _Pragma("unroll")                                                     \
        for (int r = 0; r < 2; ++r)                                           \
            gload16(BT + bOff[r] + (koff), &sm[buf][8192] + (r * 512 + wid * 64) * 8); \
    }

    W2_STAGE(0, 0)
    if (K > 64) W2_STAGE(1, 64)
    asm volatile("s_waitcnt vmcnt(4)" ::: "memory");
    SBAR();

    int cur = 0;
    for (int k0 = 0; k0 < K; k0 += 64) {
        const int nx2 = (cur >= 1) ? cur - 1 : cur + 2;   // (cur+2)%3
        if (k0 + 128 < K) W2_STAGE(nx2, k0 + 128)

        const u16* smA = &sm[cur][0];
        const u16* smB = &sm[cur][8192];
#pragma unroll
        for (int ks = 0; ks < 2; ++ks) {
            bf16x8 af[4], bfr[2];
#pragma unroll
            for (int mi = 0; mi < 4; ++mi) {
                const int row = wr * 64 + mi * 16 + r16;
                af[mi] = *(const bf16x8*)
                    &smA[row * 64 + (((ks * 4 + g) ^ (row & 7)) * 8)];
            }
#pragma unroll
            for (int ni = 0; ni < 2; ++ni) {
                const int row = wc * 32 + ni * 16 + r16;
                bfr[ni] = *(const bf16x8*)
                    &smB[row * 64 + (((ks * 4 + g) ^ (row & 7)) * 8)];
            }
            __builtin_amdgcn_s_setprio(1);
#pragma unroll
            for (int mi = 0; mi < 4; ++mi)
#pragma unroll
                for (int ni = 0; ni < 2; ++ni)
                    acc[mi][ni] = __builtin_amdgcn_mfma_f32_16x16x32_bf16(
                        af[mi], bfr[ni], acc[mi][ni], 0, 0, 0);
            __builtin_amdgcn_s_setprio(0);
        }

        if (k0 + 128 < K)      asm volatile("s_waitcnt vmcnt(4)" ::: "memory");
        else if (k0 + 64 < K)  asm volatile("s_waitcnt vmcnt(0)" ::: "memory");
        SBAR();
        cur = (cur == 2) ? 0 : cur + 1;
    }
#undef W2_STAGE

    u16* Cb = C0; const float* bp = bias0; long coff = 0;
    if (NSPLIT == 3) {
        const int grp = (int)(bn >> 10);
        if (grp == 1)      { Cb = C1; bp = bias1; }
        else if (grp == 2) { Cb = C2; bp = bias2; }
        coff = (long)grp << 10;
    }
    const long crow0 = bm + wr * 64 + g * 4;
    const long ccol0 = bn + wc * 32 + r16 - coff;
#pragma unroll
    for (int ni = 0; ni < 2; ++ni) {
        const long col = ccol0 + ni * 16;
        const float bv = bp[col];
#pragma unroll
        for (int mi = 0; mi < 4; ++mi) {
#pragma unroll
            for (int j = 0; j < 4; ++j) {
                const long row = crow0 + mi * 16 + j;
                float v = acc[mi][ni][j] + bv;
                if (RELU) v = fmaxf(v, 0.f);
                Cb[row * (long)ldc + col] = f2b(v);
            }
        }
    }
}

// ---------------------------------------------------------------------------
// Fused attention, KBLK=128; plain cached f32x4 attn stores (R16-confirmed).
//   pass 1: K-only tiles, 3 buffers -> counted vmcnt(4); pass-2 tile 0
//           prefetched during pass-1's last tile.
//   pass 2: K+V tiles, 2 buffers (parity-flipped); vmcnt(16) leaves the
//           current tile's attn stores in flight.
// ---------------------------------------------------------------------------
#define QBLK 128
#define KB2 128
#define NT2 (SEQ / KB2)
#define C2E 0.18033688f   /* 0.125 * log2(e) */

__global__ __launch_bounds__(256) void flash_attn(
    const u16* __restrict__ Qg, const u16* __restrict__ Kg,
    const u16* __restrict__ Vt, float* __restrict__ attn,
    u16* __restrict__ ctx)
{
    __shared__ u16 smem[32768];
    __shared__ u16 Ps[4][2048];

    const int tid = threadIdx.x;
    const int w = tid >> 6, l = tid & 63;
    const int r16 = l & 15, g = l >> 4;

    const int wg = (blockIdx.x & 7) * (gridDim.x >> 3) + (blockIdx.x >> 3);
    const int qb = wg & 15, z = wg >> 4;
    const int b = z >> 4, h = z & 15;
    const long q0 = (long)qb * QBLK;

    const long kBase = ((long)b * SEQ) * D_MODEL + h * DK;
    const long vBase = (long)z * DK * SEQ;

    u16* const Qs = smem + 24576;       // buf1 V region (dead during init)

#pragma unroll
    for (int r = 0; r < 4; ++r) {
        int c = r * 256 + tid;
        int row = c >> 3, bl = c & 7;
        gload16(Qg + ((long)b * SEQ + q0 + row) * D_MODEL + h * DK + ((bl ^ (row & 7)) * 8),
                Qs + (r * 256 + w * 64) * 8);
    }
#define STAGE_K(dst, kro)                                                     \
    {                                                                         \
        _Pragma("unroll")                                                     \
        for (int r = 0; r < 4; ++r) {                                         \
            int c = r * 256 + tid;                                            \
            int row = c >> 3, bl = c & 7;                                     \
            gload16(Kg + kBase + ((kro) + row) * (long)D_MODEL + ((bl ^ (row & 7)) * 8), \
                    (dst) + (r * 256 + w * 64) * 8);                          \
        }                                                                     \
    }
#define STAGE_V(dst, kro)                                                     \
    {                                                                         \
        _Pragma("unroll")                                                     \
        for (int r = 0; r < 4; ++r) {                                         \
            int c = r * 256 + tid;                                            \
            int row = c >> 4, bl = c & 15;                                    \
            gload16(Vt + vBase + (long)row * SEQ + (kro) + ((bl ^ (row & 15)) * 8), \
                    (dst) + (r * 256 + w * 64) * 8);                          \
        }                                                                     \
    }

    STAGE_K(smem, 0)                    // kb0 = smem+0
    STAGE_K(smem + 16384, KB2)          // kb1 = smem+16384
    __syncthreads();

    bf16x8 qf[2][2];                    // [qi][ks], B-operand in both passes
#pragma unroll
    for (int qi = 0; qi < 2; ++qi)
#pragma unroll
        for (int ks = 0; ks < 2; ++ks)
            qf[qi][ks] = *(const bf16x8*)
                &Qs[(w * 32 + qi * 16 + r16) * 64 + (((ks * 4 + g) ^ (r16 & 7)) * 8)];
    __syncthreads();                    // all waves hoisted; Q region reusable

    // ---------------- pass 1: l = sum exp(s/8)  (3-deep K pipeline) ----------
    float lrun[2] = {0.f, 0.f};

    for (int t = 0; t < NT2; ++t) {
        // kb[i%3]: 0 -> smem+0, 1 -> smem+16384, 2 -> smem+8192 (buf0 V region)
        const int m3n = (t + 2) % 3;
        u16* kdst = (m3n == 0) ? smem : (m3n == 1) ? smem + 16384 : smem + 8192;
        if (t + 2 < NT2) STAGE_K(kdst, (long)(t + 2) * KB2)
        if (t == NT2 - 1) {             // prefetch pass-2 tile 0 (buf1 free)
            STAGE_K(smem + 16384, 0)
            STAGE_V(smem + 24576, 0)
        }
        const int m3c = t % 3;
        const u16* kcur = (m3c == 0) ? smem : (m3c == 1) ? smem + 16384 : smem + 8192;

#pragma unroll
        for (int sub = 0; sub < 2; ++sub) {
            f32x4 sT[4][2];
#pragma unroll
            for (int ki = 0; ki < 4; ++ki)
#pragma unroll
                for (int qi = 0; qi < 2; ++qi) sT[ki][qi] = (f32x4){0.f, 0.f, 0.f, 0.f};

            __builtin_amdgcn_s_setprio(1);
#pragma unroll
            for (int ks = 0; ks < 2; ++ks) {
                bf16x8 kf[4];
#pragma unroll
                for (int ki = 0; ki < 4; ++ki)
                    kf[ki] = *(const bf16x8*)
                        &kcur[(sub * 64 + ki * 16 + r16) * 64 + (((ks * 4 + g) ^ (r16 & 7)) * 8)];
#pragma unroll
                for (int ki = 0; ki < 4; ++ki)
#pragma unroll
                    for (int qi = 0; qi < 2; ++qi)
                        sT[ki][qi] = __builtin_amdgcn_mfma_f32_16x16x32_bf16(
                            kf[ki], qf[qi][ks], sT[ki][qi], 0, 0, 0);
            }
            __builtin_amdgcn_s_setprio(0);

#pragma unroll
            for (int qi = 0; qi < 2; ++qi) {
                float ls = 0.f;
#pragma unroll
                for (int ki = 0; ki < 4; ++ki)
#pragma unroll
                    for (int j = 0; j < 4; ++j)
                        ls += exp2f(sT[ki][qi][j] * C2E);
                ls += __shfl_xor(ls, 16);
                ls += __shfl_xor(ls, 32);
                lrun[qi] += ls;
            }
        }
        if (t + 2 < NT2)      asm volatile("s_waitcnt vmcnt(4)" ::: "memory");
        else if (t + 1 < NT2) asm volatile("s_waitcnt vmcnt(0)" ::: "memory");
        if (t + 1 < NT2) SBAR();
    }

    const float il[2] = {1.0f / lrun[0], 1.0f / lrun[1]};   // q = r16, in-register

    // pass-2 tile 0 was prefetched during pass-1's last tile
    asm volatile("s_waitcnt vmcnt(0)" ::: "memory");
    SBAR();

    // ---------------- pass 2: S^T; plain f32x4 P writes + PV ----------------
    f32x4 acc2[2][4];
#pragma unroll
    for (int mi = 0; mi < 2; ++mi)
#pragma unroll
        for (int ni = 0; ni < 4; ++ni) acc2[mi][ni] = (f32x4){0.f, 0.f, 0.f, 0.f};

    const long arow0 = ((long)z * SEQ + q0 + w * 32) * (long)SEQ;

    for (int t = 0; t < NT2; ++t) {
        const int k0 = t * KB2;
        if (t + 1 < NT2) {
            u16* dst = smem + (t & 1) * 16384;          // parity-flipped
            STAGE_K(dst, (long)(t + 1) * KB2)
            STAGE_V(dst + 8192, (long)(t + 1) * KB2)
        }
        const u16* kcur = smem + (((t + 1) & 1)) * 16384;
        const u16* vcur = kcur + 8192;

#pragma unroll
        for (int sub = 0; sub < 2; ++sub) {
            f32x4 sT[4][2];
#pragma unroll
            for (int ki = 0; ki < 4; ++ki)
#pragma unroll
                for (int qi = 0; qi < 2; ++qi) sT[ki][qi] = (f32x4){0.f, 0.f, 0.f, 0.f};

            __builtin_amdgcn_s_setprio(1);
#pragma unroll
            for (int ks = 0; ks < 2; ++ks) {
                bf16x8 kf[4];
#pragma unroll
                for (int ki = 0; ki < 4; ++ki)
                    kf[ki] = *(const bf16x8*)
                        &kcur[(sub * 64 + ki * 16 + r16) * 64 + (((ks * 4 + g) ^ (r16 & 7)) * 8)];
#pragma unroll
                for (int ki = 0; ki < 4; ++ki)
#pragma unroll
                    for (int qi = 0; qi < 2; ++qi)
                        sT[ki][qi] = __builtin_amdgcn_mfma_f32_16x16x32_bf16(
                            kf[ki], qf[qi][ks], sT[ki][qi], 0, 0, 0);
            }
            __builtin_amdgcn_s_setprio(0);

#pragma unroll
            for (int qi = 0; qi < 2; ++qi) {
                const long ar = arow0 + (long)(qi * 16 + r16) * SEQ + k0 + sub * 64 + g * 4;
                const int prow = (qi * 16 + r16) * 64;
#pragma unroll
                for (int ki = 0; ki < 4; ++ki) {
                    f32x4 p;
                    p[0] = exp2f(sT[ki][qi][0] * C2E) * il[qi];
                    p[1] = exp2f(sT[ki][qi][1] * C2E) * il[qi];
                    p[2] = exp2f(sT[ki][qi][2] * C2E) * il[qi];
                    p[3] = exp2f(sT[ki][qi][3] * C2E) * il[qi];
                    *(f32x4*)&attn[ar + ki * 16] = p;           // plain cached store
                    us4 pb;
                    pb[0] = f2b(p[0]); pb[1] = f2b(p[1]);
                    pb[2] = f2b(p[2]); pb[3] = f2b(p[3]);
                    const int kblk = 2 * ki + (g >> 1);
                    *(us4*)&Ps[w][prow + ((kblk ^ (r16 & 7)) << 3) + ((g & 1) << 2)] = pb;
                }
            }

            __builtin_amdgcn_s_setprio(1);
#pragma unroll
            for (int ks = 0; ks < 2; ++ks) {
                bf16x8 pf[2], vf[4];
#pragma unroll
                for (int mi = 0; mi < 2; ++mi)
                    pf[mi] = *(const bf16x8*)
                        &Ps[w][(mi * 16 + r16) * 64 + (((ks * 4 + g) ^ (r16 & 7)) << 3)];
#pragma unroll
                for (int ni = 0; ni < 4; ++ni) {
                    const int row = ni * 16 + r16;
                    const int slot = sub * 8 + ks * 4 + g;
                    vf[ni] = *(const bf16x8*)
                        &vcur[row * 128 + ((slot ^ (row & 15)) * 8)];
                }
#pragma unroll
                for (int mi = 0; mi < 2; ++mi)
#pragma unroll
                    for (int ni = 0; ni < 4; ++ni)
                        acc2[mi][ni] = __builtin_amdgcn_mfma_f32_16x16x32_bf16(
                            pf[mi], vf[ni], acc2[mi][ni], 0, 0, 0);
            }
            __builtin_amdgcn_s_setprio(0);
        }

        if (t + 1 < NT2) {
            asm volatile("s_waitcnt vmcnt(16)" ::: "memory");
            SBAR();
        }
    }
#undef STAGE_K
#undef STAGE_V

    // ---- ctx epilogue (bf16); C layout: row=q=g*4+j(+16mi), col=d=ni*16+r16
#pragma unroll
    for (int mi = 0; mi < 2; ++mi)
#pragma unroll
        for (int j = 0; j < 4; ++j) {
            const long grow = (long)b * SEQ + q0 + w * 32 + mi * 16 + g * 4 + j;
#pragma unroll
            for (int ni = 0; ni < 4; ++ni)
                ctx[grow * D_MODEL + h * DK + ni * 16 + r16] = f2b(acc2[mi][ni][j]);
        }
}

// ---------------------------------------------------------------------------
// Merged preprocessing: x cvt + 4x square-W transpose + W1/W2 transpose.
// All f32 sources are single-touch -> non-temporal loads.
// ---------------------------------------------------------------------------
__device__ __forceinline__ void tr32(
    const float* __restrict__ W, u16* __restrict__ Wt, int R, int C,
    int bx, int by, int tx, int ty, float (*t)[33])
{
    const long c = (long)bx * 32 + tx;
    const long r0 = (long)by * 32;
#pragma unroll
    for (int j = 0; j < 32; j += 8)
        t[ty + j][tx] = __builtin_nontemporal_load(&W[(r0 + ty + j) * C + c]);
    __syncthreads();
    const long r = r0 + tx;
#pragma unroll
    for (int j = 0; j < 32; j += 8)
        Wt[((long)bx * 32 + ty + j) * R + r] = f2b(t[tx][ty + j]);
}

__global__ __launch_bounds__(256) void preproc(
    const float* __restrict__ x, u16* __restrict__ x_bf,
    const float* __restrict__ Wq, const float* __restrict__ Wk,
    const float* __restrict__ Wv, const float* __restrict__ Wo,
    u16* __restrict__ Wqkvo_t,
    const float* __restrict__ W1, u16* __restrict__ W1t,
    const float* __restrict__ W2, u16* __restrict__ W2t)
{
    __shared__ float t[32][33];
    int bid = blockIdx.x;
    const int tx = threadIdx.x & 31, ty = threadIdx.x >> 5;

    if (bid < 2048) {
        long i = ((long)bid * 256 + threadIdx.x) * 8;
        f32x4 a = __builtin_nontemporal_load((const f32x4*)(x + i));
        f32x4 b = __builtin_nontemporal_load((const f32x4*)(x + i + 4));
        us8 o;
        o[0] = f2b(a[0]); o[1] = f2b(a[1]); o[2] = f2b(a[2]); o[3] = f2b(a[3]);
        o[4] = f2b(b[0]); o[5] = f2b(b[1]); o[6] = f2b(b[2]); o[7] = f2b(b[3]);
        *(us8*)(x_bf + i) = o;
        return;
    }
    bid -= 2048;
    if (bid < 4096) {
        const int z = bid >> 10, rem = bid & 1023;
        const float* W = (z == 0) ? Wq : (z == 1) ? Wk : (z == 2) ? Wv : Wo;
        tr32(W, Wqkvo_t + (size_t)z * D_MODEL * D_MODEL, D_MODEL, D_MODEL,
             rem & 31, rem >> 5, tx, ty, t);
        return;
    }
    bid -= 4096;
    if (bid < 4096) {
        tr32(W1, W1t, D_MODEL, D_FF, bid & 127, bid >> 7, tx, ty, t);
        return;
    }
    bid -= 4096;
    {
        tr32(W2, W2t, D_FF, D_MODEL, bid & 31, bid >> 5, tx, ty, t);
    }
}

// ---------------------------------------------------------------------------
// V_bf [b*2048+k][1024] -> Vt [(b*16+h)*64+d][2048]   (per-head transpose)
// ---------------------------------------------------------------------------
__global__ __launch_bounds__(256) void transpose_v(
    const u16* __restrict__ V, u16* __restrict__ Vt)
{
    __shared__ u16 t[32][33];
    const int z = blockIdx.z, b = z >> 4, h = z & 15;
    const int tx = threadIdx.x & 31, ty = threadIdx.x >> 5;
    const long k0 = (long)blockIdx.x * 32;
    const long d0 = (long)blockIdx.y * 32;
#pragma unroll
    for (int j = 0; j < 32; j += 8)
        t[ty + j][tx] = V[((long)b * SEQ + k0 + ty + j) * D_MODEL + h * DK + d0 + tx];
    __syncthreads();
#pragma unroll
    for (int j = 0; j < 32; j += 8)
        Vt[((long)z * DK + d0 + ty + j) * SEQ + k0 + tx] = t[tx][ty + j];
}

// ---------------------------------------------------------------------------
// out = LayerNorm(a_bf + b_bf) * g + be ; one wave per row.
//   OM: 0 = f32 out, 1 = bf16 out.
// ---------------------------------------------------------------------------
template<int OM>
__global__ __launch_bounds__(256) void add_ln_kernel(
    const u16* __restrict__ a, const u16* __restrict__ b,
    const float* __restrict__ g, const float* __restrict__ be,
    void* __restrict__ outp)
{
    const int l = threadIdx.x & 63, w = threadIdx.x >> 6;
    const long row = (long)blockIdx.x * 4 + w;
    const long base = row * D_MODEL;

    float xv[16];
#pragma unroll
    for (int c = 0; c < 2; ++c) {
        const long off = c * 512 + l * 8;
        us8 av = *(const us8*)(a + base + off);
        us8 bv = *(const us8*)(b + base + off);
#pragma unroll
        for (int i = 0; i < 8; ++i)
            xv[c * 8 + i] = b2f(av[i]) + b2f(bv[i]);
    }

    float s = 0.f;
#pragma unroll
    for (int i = 0; i < 16; ++i) s += xv[i];
#pragma unroll
    for (int off = 1; off < 64; off <<= 1) s += __shfl_xor(s, off);
    const float mean = s * (1.0f / D_MODEL);

    float ss = 0.f;
#pragma unroll
    for (int i = 0; i < 16; ++i) {
        xv[i] -= mean;
        ss += xv[i] * xv[i];
    }
#pragma unroll
    for (int off = 1; off < 64; off <<= 1) ss += __shfl_xor(ss, off);
    const float rs = rsqrtf(ss * (1.0f / D_MODEL) + EPS);

#pragma unroll
    for (int c = 0; c < 2; ++c) {
        const long off = c * 512 + l * 8;
        float4 g0 = *(const float4*)(g + off);
        float4 g1 = *(const float4*)(g + off + 4);
        float4 b0 = *(const float4*)(be + off);
        float4 b1 = *(const float4*)(be + off + 4);
        float o[8];
        o[0] = xv[c*8+0] * rs * g0.x + b0.x;
        o[1] = xv[c*8+1] * rs * g0.y + b0.y;
        o[2] = xv[c*8+2] * rs * g0.z + b0.z;
        o[3] = xv[c*8+3] * rs * g0.w + b0.w;
        o[4] = xv[c*8+4] * rs * g1.x + b1.x;
        o[5] = xv[c*8+5] * rs * g1.y + b1.y;
        o[6] = xv[c*8+6] * rs * g1.z + b1.z;
        o[7] = xv[c*8+7] * rs * g1.w + b1.w;
        if (OM == 0) {
            float4 v0 = {o[0], o[1], o[2], o[3]};
            float4 v1 = {o[4], o[5], o[6], o[7]};
            *(float4*)((float*)outp + base + off) = v0;
            *(float4*)((float*)outp + base + off + 4) = v1;
        } else {
            us8 ob;
#pragma unroll
            for (int i = 0; i < 8; ++i) ob[i] = f2b(o[i]);
            *(us8*)((u16*)outp + base + off) = ob;
        }
    }
}

// ---------------------------------------------------------------------------
extern "C" void kernel_launch(void* const* d_in, const int* in_sizes, int n_in,
                              void* d_out, int out_size, void* d_ws, size_t ws_size,
                              hipStream_t stream)
{
    const float* x   = (const float*)d_in[0];
    const float* Wq  = (const float*)d_in[1];
    const float* bq  = (const float*)d_in[2];
    const float* Wk  = (const float*)d_in[3];
    const float* bk  = (const float*)d_in[4];
    const float* Wv  = (const float*)d_in[5];
    const float* bv  = (const float*)d_in[6];
    const float* Wo  = (const float*)d_in[7];
    const float* bo  = (const float*)d_in[8];
    const float* W1  = (const float*)d_in[9];
    const float* b1  = (const float*)d_in[10];
    const float* W2  = (const float*)d_in[11];
    const float* b2  = (const float*)d_in[12];
    const float* g1  = (const float*)d_in[13];
    const float* be1 = (const float*)d_in[14];
    const float* g2  = (const float*)d_in[15];
    const float* be2 = (const float*)d_in[16];

    float* out  = (float*)d_out;
    float* attn = out + (size_t)BATCH * SEQ * D_MODEL;

    char* ws = (char*)d_ws;
    const size_t MB = 1u << 20;
    u16* x_bf    = (u16*)(ws);              // 0-8 MB   (live until LN1)
    u16* Q_bf    = (u16*)(ws + 8 * MB);     // 8-16
    u16* K_bf    = (u16*)(ws + 16 * MB);    // 16-24    (then h_bf)
    u16* Vt      = (u16*)(ws + 24 * MB);    // 24-32    (then ff2_bf)
    u16* V_bf    = (u16*)(ws + 32 * MB);    // 32-40    (then ao_bf)
    u16* Wqkvo_t = (u16*)(ws + 40 * MB);    // 40-48
    u16* W1t     = (u16*)(ws + 48 * MB);    // 48-56
    u16* W2t     = (u16*)(ws + 56 * MB);    // 56-64
    u16* ff1_bf  = (u16*)(ws + 64 * MB);    // 64-96
    u16* ctx_bf  = (u16*)(ws + 96 * MB);    // 96-104
    u16* Wot     = Wqkvo_t + (size_t)3 * D_MODEL * D_MODEL;
    u16* h_bf    = K_bf;                    // K dead after flash_attn
    u16* ao_bf   = V_bf;                    // V_bf dead after transpose_v
    u16* ff2_bf  = Vt;                      // Vt dead after flash_attn

    const int M = BATCH * SEQ;              // 4096
    dim3 T(256);

    preproc<<<dim3(2048 + 3 * 4096), T, 0, stream>>>(
        x, x_bf, Wq, Wk, Wv, Wo, Wqkvo_t, W1, W1t, W2, W2t);

    // --- fused QKV projection: N=3072, w2 structure (BK=64, 512 thr) ---
    gemm_w2<false, 3><<<dim3((M / 128) * 24), dim3(512), 0, stream>>>(
        x_bf, Wqkvo_t, bq, bk, bv, Q_bf, K_bf, V_bf,
        D_MODEL, D_MODEL, D_MODEL, D_MODEL, 24);

    transpose_v<<<dim3(SEQ / 32, DK / 32, BATCH * NUM_HEADS), T, 0, stream>>>(V_bf, Vt);

    flash_attn<<<dim3((SEQ / QBLK) * BATCH * NUM_HEADS), T, 0, stream>>>(
        Q_bf, K_bf, Vt, attn, ctx_bf);

    // --- Wo projection (bf16 out; 128x128/BK=64, 256 blocks x 8 waves) ---
    gemm_w2<false, 1><<<dim3((M / 128) * 8), dim3(512), 0, stream>>>(
        ctx_bf, Wot, bo, nullptr, nullptr, ao_bf, nullptr, nullptr,
        D_MODEL, D_MODEL, D_MODEL, D_MODEL, 8);

    add_ln_kernel<1><<<dim3(M / 4), T, 0, stream>>>(x_bf, ao_bf, g1, be1, h_bf);

    // --- FF1 (256² 4-phase, 256 blocks x 8 waves) ---
    gemm256<D_MODEL, true><<<dim3((M / 256) * (D_FF / 256)), dim3(512), 0, stream>>>(
        h_bf, W1t, b1, ff1_bf, D_FF, D_FF / 256);

    // --- FF2 (bf16 out; 128x128/BK=64, 256 blocks x 8 waves) ---
    gemm_w2<false, 1><<<dim3((M / 128) * 8), dim3(512), 0, stream>>>(
        ff1_bf, W2t, b2, nullptr, nullptr, ff2_bf, nullptr, nullptr,
        D_FF, D_FF, D_MODEL, D_FF, 8);

    add_ln_kernel<0><<<dim3(M / 4), T, 0, stream>>>(h_bf, ff2_bf, g2, be2, out);
}

// Round 19
// 367.063 us; speedup vs baseline: 1.0111x; 1.0111x over previous
//
#include <hip/hip_runtime.h>
#include <cstddef>
#include <cstdint>

#define D_MODEL 1024
#define NUM_HEADS 16
#define DK 64
#define D_FF 4096
#define SEQ 2048
#define BATCH 2
#define EPS 1e-5f

typedef unsigned short u16;
typedef __attribute__((ext_vector_type(8))) short bf16x8;
typedef __attribute__((ext_vector_type(8))) unsigned short us8;
typedef __attribute__((ext_vector_type(4))) unsigned short us4;
typedef __attribute__((ext_vector_type(4))) float f32x4;

#define SBAR() asm volatile("s_barrier" ::: "memory")

__device__ __forceinline__ u16 f2b(float f) {
    unsigned u = __float_as_uint(f);
    u += 0x7fffu + ((u >> 16) & 1u);          // round-to-nearest-even
    return (u16)(u >> 16);
}
__device__ __forceinline__ float b2f(u16 v) {
    return __uint_as_float((unsigned)v << 16);
}

__device__ __forceinline__ void gload16(const void* g, void* l) {
    __builtin_amdgcn_global_load_lds(
        (const __attribute__((address_space(1))) void*)g,
        (__attribute__((address_space(3))) void*)l, 16, 0, 0);
}

// ===========================================================================
// 256x256 8-wave GEMM, 4-phase/K-tile, counted vmcnt, LDS swizzle, setprio,
// bijective XCD swizzle.  (used for FF1: grid 256 = 1 block/CU, 8 waves)
// ===========================================================================
__device__ __forceinline__ void stage_half(
    const u16* __restrict__ g, int ld, long kbase, int h,
    u16* dst, int tid, int wid)
{
#pragma unroll
    for (int r = 0; r < 2; ++r) {
        const int ci  = r * 512 + tid;
        const int row = ci >> 2;
        const int wd  = ci & 3;
        const int f   = (row + (row >> 2)) & 3;
        const long src = (long)row * ld + kbase + (long)(h * 4 + (wd ^ f)) * 8;
        gload16(g + src, dst + (r * 512 + wid * 64) * 8);
    }
}

__device__ __forceinline__ bf16x8 frag64(const u16* base, int ks, int row, int g) {
    const int f = (row + (row >> 2)) & 3;
    return *(const bf16x8*)&base[ks * 8192 + row * 32 + ((g ^ f) * 8)];
}

template<int KTOT, bool RELU>
__global__ __launch_bounds__(512, 2) void gemm256(
    const u16* __restrict__ Abf, const u16* __restrict__ BT,
    const float* __restrict__ bias0, u16* __restrict__ C0,
    int ldc, int nx)
{
    constexpr int NT = KTOT / 64;
    __shared__ u16 lds[2][32768];

    const int tid = threadIdx.x;
    const int wid = tid >> 6, l = tid & 63;
    const int r16 = l & 15, g = l >> 4;
    const int wr = wid >> 2, wc = wid & 3;

    const int nwg = gridDim.x;
    const int q = nwg >> 3, rr = nwg & 7;
    const int xcd = blockIdx.x & 7, idx = blockIdx.x >> 3;
    const int wg = (xcd < rr ? xcd * (q + 1) : rr * (q + 1) + (xcd - rr) * q) + idx;
    const long bm = (long)(wg / nx) * 256;
    const long bn = (long)(wg % nx) * 256;

    const u16* Ag = Abf + bm * KTOT;
    const u16* Bg = BT + bn * KTOT;

    f32x4 acc[8][4];
#pragma unroll
    for (int i = 0; i < 8; ++i)
#pragma unroll
        for (int n = 0; n < 4; ++n)
            acc[i][n] = (f32x4){0.f, 0.f, 0.f, 0.f};

    stage_half(Ag, KTOT, 0, 0, &lds[0][0],     tid, wid);
    stage_half(Ag, KTOT, 0, 1, &lds[0][8192],  tid, wid);
    stage_half(Bg, KTOT, 0, 0, &lds[0][16384], tid, wid);
    stage_half(Bg, KTOT, 0, 1, &lds[0][24576], tid, wid);
    if (NT > 1) {
        stage_half(Ag, KTOT, 64, 0, &lds[1][0],     tid, wid);
        stage_half(Bg, KTOT, 64, 0, &lds[1][16384], tid, wid);
    }
    asm volatile("s_waitcnt vmcnt(4)" ::: "memory");
    SBAR();

    for (int t = 0; t < NT; ++t) {
        u16* cur = &lds[t & 1][0];
        u16* nxt = &lds[(t + 1) & 1][0];
        const long k1 = (long)(t + 1) * 64;
        const long k2 = (long)(t + 2) * 64;
        const bool s1 = (t + 1 < NT), s2 = (t + 2 < NT);

        bf16x8 a0[4], b0[4];
#pragma unroll
        for (int i = 0; i < 4; ++i) {
            a0[i] = frag64(cur,         0, wr * 128 + i * 16 + r16, g);
            b0[i] = frag64(cur + 16384, 0, wc * 64  + i * 16 + r16, g);
        }
        if (s1) stage_half(Ag, KTOT, k1, 1, nxt + 8192, tid, wid);
        SBAR();
        __builtin_amdgcn_s_setprio(1);
#pragma unroll
        for (int i = 0; i < 4; ++i)
#pragma unroll
            for (int n = 0; n < 4; ++n)
                acc[i][n] = __builtin_amdgcn_mfma_f32_16x16x32_bf16(
                    a0[i], b0[n], acc[i][n], 0, 0, 0);
        __builtin_amdgcn_s_setprio(0);
        SBAR();

        bf16x8 a1[4];
#pragma unroll
        for (int i = 0; i < 4; ++i)
            a1[i] = frag64(cur, 0, wr * 128 + (i + 4) * 16 + r16, g);
        if (s1) stage_half(Bg, KTOT, k1, 1, nxt + 24576, tid, wid);
        SBAR();
        __builtin_amdgcn_s_setprio(1);
#pragma unroll
        for (int i = 0; i < 4; ++i)
#pragma unroll
            for (int n = 0; n < 4; ++n)
                acc[i + 4][n] = __builtin_amdgcn_mfma_f32_16x16x32_bf16(
                    a1[i], b0[n], acc[i + 4][n], 0, 0, 0);
        __builtin_amdgcn_s_setprio(0);
        SBAR();

        bf16x8 a2[4], b1[4];
#pragma unroll
        for (int i = 0; i < 4; ++i) {
            a2[i] = frag64(cur,         1, wr * 128 + i * 16 + r16, g);
            b1[i] = frag64(cur + 16384, 1, wc * 64  + i * 16 + r16, g);
        }
        if (s2) stage_half(Ag, KTOT, k2, 0, cur, tid, wid);
        SBAR();
        __builtin_amdgcn_s_setprio(1);
#pragma unroll
        for (int i = 0; i < 4; ++i)
#pragma unroll
            for (int n = 0; n < 4; ++n)
                acc[i][n] = __builtin_amdgcn_mfma_f32_16x16x32_bf16(
                    a2[i], b1[n], acc[i][n], 0, 0, 0);
        __builtin_amdgcn_s_setprio(0);
        SBAR();

        bf16x8 a3[4];
#pragma unroll
        for (int i = 0; i < 4; ++i)
            a3[i] = frag64(cur, 1, wr * 128 + (i + 4) * 16 + r16, g);
        if (s2) stage_half(Bg, KTOT, k2, 0, cur + 16384, tid, wid);
        SBAR();
        __builtin_amdgcn_s_setprio(1);
#pragma unroll
        for (int i = 0; i < 4; ++i)
#pragma unroll
            for (int n = 0; n < 4; ++n)
                acc[i + 4][n] = __builtin_amdgcn_mfma_f32_16x16x32_bf16(
                    a3[i], b1[n], acc[i + 4][n], 0, 0, 0);
        __builtin_amdgcn_s_setprio(0);
        if (s2)      asm volatile("s_waitcnt vmcnt(4)" ::: "memory");
        else if (s1) asm volatile("s_waitcnt vmcnt(0)" ::: "memory");
        SBAR();
    }

    const long crow0 = bm + wr * 128 + g * 4;
    const long ccol0 = bn + wc * 64 + r16;
#pragma unroll
    for (int n = 0; n < 4; ++n) {
        const long col = ccol0 + n * 16;
        const float bv = bias0[col];
#pragma unroll
        for (int i = 0; i < 8; ++i)
#pragma unroll
            for (int j = 0; j < 4; ++j) {
                const long row = crow0 + i * 16 + j;
                float v = acc[i][n][j] + bv;
                if (RELU) v = fmaxf(v, 0.f);
                C0[row * (long)ldc + col] = f2b(v);
            }
    }
}

// ---------------------------------------------------------------------------
// Generic bf16 MFMA GEMM (128², XCD swizzle), bf16 out — 3-BUFFER pipeline
// with counted vmcnt (BK=32), 256 threads, 48 KB LDS -> 3 blocks/CU.
// NSPLIT=3 (QKV) splits cols into C0/C1/C2 (coalesced, ldc=1024 each).
// ---------------------------------------------------------------------------
template<bool RELU, int NSPLIT>
__global__ __launch_bounds__(256) void gemm_mfma(
    const u16* __restrict__ Abf, const u16* __restrict__ BT,
    const float* __restrict__ bias0, const float* __restrict__ bias1,
    const float* __restrict__ bias2,
    u16* __restrict__ C0, u16* __restrict__ C1, u16* __restrict__ C2,
    int lda, int ldb, int ldc, int K, int nx)
{
    constexpr int BM = 128, BN = 128;
    constexpr int MI = 4, NI = 4;      // 2x2 waves, 64x64 per wave
    constexpr int RA = 2, RB = 2;
    constexpr int TILE = (BM + BN) * 32;

    __shared__ u16 sm[3][TILE];        // 48 KB

    const int tid = threadIdx.x;
    const int w = tid >> 6, l = tid & 63;
    const int r16 = l & 15, g = l >> 4;
    const int wr = w >> 1, wc = w & 1;

    const int nwg = gridDim.x;
    const int q = nwg >> 3, rr = nwg & 7;
    const int xcd = blockIdx.x & 7, idx = blockIdx.x >> 3;
    const int wg = (xcd < rr ? xcd * (q + 1) : rr * (q + 1) + (xcd - rr) * q) + idx;
    const long bm = (long)(wg / nx) * BM;
    const long bn = (long)(wg % nx) * BN;

    f32x4 acc[MI][NI];
#pragma unroll
    for (int mi = 0; mi < MI; ++mi)
#pragma unroll
        for (int ni = 0; ni < NI; ++ni)
            acc[mi][ni] = (f32x4){0.f, 0.f, 0.f, 0.f};

    long aOff[RA], bOff[RB];
#pragma unroll
    for (int r = 0; r < RA; ++r) {
        int c = r * 256 + tid;
        aOff[r] = (long)(bm + (c >> 2)) * lda + (c & 3) * 8;
    }
#pragma unroll
    for (int r = 0; r < RB; ++r) {
        int c = r * 256 + tid;
        bOff[r] = (long)(bn + (c >> 2)) * ldb + (c & 3) * 8;
    }

    // prologue: tiles 0 and 1 (4 loads each); confirm tile 0
#pragma unroll
    for (int r = 0; r < RA; ++r)
        gload16(Abf + aOff[r], &sm[0][0] + (r * 256 + w * 64) * 8);
#pragma unroll
    for (int r = 0; r < RB; ++r)
        gload16(BT + bOff[r], &sm[0][BM * 32] + (r * 256 + w * 64) * 8);
    if (K > 32) {
#pragma unroll
        for (int r = 0; r < RA; ++r)
            gload16(Abf + aOff[r] + 32, &sm[1][0] + (r * 256 + w * 64) * 8);
#pragma unroll
        for (int r = 0; r < RB; ++r)
            gload16(BT + bOff[r] + 32, &sm[1][BM * 32] + (r * 256 + w * 64) * 8);
    }
    asm volatile("s_waitcnt vmcnt(4)" ::: "memory");
    SBAR();

    int cur = 0;
    for (int k0 = 0; k0 < K; k0 += 32) {
        const int nx2 = (cur >= 1) ? cur - 1 : cur + 2;   // (cur+2)%3
        if (k0 + 64 < K) {
#pragma unroll
            for (int r = 0; r < RA; ++r)
                gload16(Abf + aOff[r] + k0 + 64, &sm[nx2][0] + (r * 256 + w * 64) * 8);
#pragma unroll
            for (int r = 0; r < RB; ++r)
                gload16(BT + bOff[r] + k0 + 64, &sm[nx2][BM * 32] + (r * 256 + w * 64) * 8);
        }

        const u16* smA = &sm[cur][0];
        const u16* smB = &sm[cur][BM * 32];
        bf16x8 af[MI], bfr[NI];
#pragma unroll
        for (int mi = 0; mi < MI; ++mi)
            af[mi] = *(const bf16x8*)&smA[(wr * 64 + mi * 16 + r16) * 32 + g * 8];
#pragma unroll
        for (int ni = 0; ni < NI; ++ni)
            bfr[ni] = *(const bf16x8*)&smB[(wc * 64 + ni * 16 + r16) * 32 + g * 8];
#pragma unroll
        for (int mi = 0; mi < MI; ++mi)
#pragma unroll
            for (int ni = 0; ni < NI; ++ni)
                acc[mi][ni] = __builtin_amdgcn_mfma_f32_16x16x32_bf16(
                    af[mi], bfr[ni], acc[mi][ni], 0, 0, 0);

        if (k0 + 64 < K)      asm volatile("s_waitcnt vmcnt(4)" ::: "memory");
        else if (k0 + 32 < K) asm volatile("s_waitcnt vmcnt(0)" ::: "memory");
        SBAR();
        cur = (cur == 2) ? 0 : cur + 1;
    }

    u16* Cb = C0; const float* bp = bias0; long coff = 0;
    if (NSPLIT == 3) {
        const int grp = (int)(bn >> 10);
        if (grp == 1)      { Cb = C1; bp = bias1; }
        else if (grp == 2) { Cb = C2; bp = bias2; }
        coff = (long)grp << 10;
    }
    const long crow0 = bm + wr * 64 + g * 4;
    const long ccol0 = bn + wc * 64 + r16 - coff;
#pragma unroll
    for (int ni = 0; ni < NI; ++ni) {
        const long col = ccol0 + ni * 16;
        const float bv = bp[col];
#pragma unroll
        for (int mi = 0; mi < MI; ++mi) {
#pragma unroll
            for (int j = 0; j < 4; ++j) {
                const long row = crow0 + mi * 16 + j;
                float v = acc[mi][ni][j] + bv;
                if (RELU) v = fmaxf(v, 0.f);
                Cb[row * (long)ldc + col] = f2b(v);
            }
        }
    }
}

// ---------------------------------------------------------------------------
// 128x128-tile GEMM, BK=64, 512 threads (8 waves, wave tile 64x32),
// 3-buffer counted vmcnt(4).  96 KB LDS -> 1 block/CU (8 waves/CU).
// Used for Wo and FF2 (N=1024): grid 256 blocks = 1/CU, deep K.
// ---------------------------------------------------------------------------
template<bool RELU>
__global__ __launch_bounds__(512) void gemm_w2(
    const u16* __restrict__ Abf, const u16* __restrict__ BT,
    const float* __restrict__ bias, u16* __restrict__ C,
    int lda, int ldb, int ldc, int K, int nx)
{
    constexpr int TILE = 16384;            // (128+128)*64 u16 = 32 KB
    __shared__ u16 sm[3][TILE];            // 96 KB

    const int tid = threadIdx.x;
    const int wid = tid >> 6, l = tid & 63;
    const int r16 = l & 15, g = l >> 4;
    const int wr = wid >> 2, wc = wid & 3;   // 2 x 4 wave grid; tile 64 x 32

    const int nwg = gridDim.x;
    const int q = nwg >> 3, rr = nwg & 7;
    const int xcd = blockIdx.x & 7, idx = blockIdx.x >> 3;
    const int wg = (xcd < rr ? xcd * (q + 1) : rr * (q + 1) + (xcd - rr) * q) + idx;
    const long bm = (long)(wg / nx) * 128;
    const long bn = (long)(wg % nx) * 128;

    f32x4 acc[4][2];
#pragma unroll
    for (int mi = 0; mi < 4; ++mi)
#pragma unroll
        for (int ni = 0; ni < 2; ++ni)
            acc[mi][ni] = (f32x4){0.f, 0.f, 0.f, 0.f};

    // staging offsets: A 128 rows x 8 slots (2 rounds), B same; slot^row&7
    long aOff[2], bOff[2];
#pragma unroll
    for (int r = 0; r < 2; ++r) {
        int c = r * 512 + tid;
        int row = c >> 3, sl = c & 7;
        aOff[r] = (long)(bm + row) * lda + (long)(sl ^ (row & 7)) * 8;
        bOff[r] = (long)(bn + row) * ldb + (long)(sl ^ (row & 7)) * 8;
    }

#define W2_STAGE(buf, koff)                                                   \
    {                                                                         \
        _Pragma("unroll")                                                     \
        for (int r = 0; r < 2; ++r)                                           \
            gload16(Abf + aOff[r] + (koff), &sm[buf][0] + (r * 512 + wid * 64) * 8); \
        _Pragma("unroll")                                                     \
        for (int r = 0; r < 2; ++r)                                           \
            gload16(BT + bOff[r] + (koff), &sm[buf][8192] + (r * 512 + wid * 64) * 8); \
    }

    W2_STAGE(0, 0)
    if (K > 64) W2_STAGE(1, 64)
    asm volatile("s_waitcnt vmcnt(4)" ::: "memory");
    SBAR();

    int cur = 0;
    for (int k0 = 0; k0 < K; k0 += 64) {
        const int nx2 = (cur >= 1) ? cur - 1 : cur + 2;   // (cur+2)%3
        if (k0 + 128 < K) W2_STAGE(nx2, k0 + 128)

        const u16* smA = &sm[cur][0];
        const u16* smB = &sm[cur][8192];
#pragma unroll
        for (int ks = 0; ks < 2; ++ks) {
            bf16x8 af[4], bfr[2];
#pragma unroll
            for (int mi = 0; mi < 4; ++mi) {
                const int row = wr * 64 + mi * 16 + r16;
                af[mi] = *(const bf16x8*)
                    &smA[row * 64 + (((ks * 4 + g) ^ (row & 7)) * 8)];
            }
#pragma unroll
            for (int ni = 0; ni < 2; ++ni) {
                const int row = wc * 32 + ni * 16 + r16;
                bfr[ni] = *(const bf16x8*)
                    &smB[row * 64 + (((ks * 4 + g) ^ (row & 7)) * 8)];
            }
            __builtin_amdgcn_s_setprio(1);
#pragma unroll
            for (int mi = 0; mi < 4; ++mi)
#pragma unroll
                for (int ni = 0; ni < 2; ++ni)
                    acc[mi][ni] = __builtin_amdgcn_mfma_f32_16x16x32_bf16(
                        af[mi], bfr[ni], acc[mi][ni], 0, 0, 0);
            __builtin_amdgcn_s_setprio(0);
        }

        if (k0 + 128 < K)      asm volatile("s_waitcnt vmcnt(4)" ::: "memory");
        else if (k0 + 64 < K)  asm volatile("s_waitcnt vmcnt(0)" ::: "memory");
        SBAR();
        cur = (cur == 2) ? 0 : cur + 1;
    }
#undef W2_STAGE

    const long crow0 = bm + wr * 64 + g * 4;
    const long ccol0 = bn + wc * 32 + r16;
#pragma unroll
    for (int ni = 0; ni < 2; ++ni) {
        const long col = ccol0 + ni * 16;
        const float bv = bias[col];
#pragma unroll
        for (int mi = 0; mi < 4; ++mi) {
#pragma unroll
            for (int j = 0; j < 4; ++j) {
                const long row = crow0 + mi * 16 + j;
                float v = acc[mi][ni][j] + bv;
                if (RELU) v = fmaxf(v, 0.f);
                C[row * (long)ldc + col] = f2b(v);
            }
        }
    }
}

// ---------------------------------------------------------------------------
// Fused attention, KBLK=128; plain cached f32x4 attn stores (R16-confirmed).
//   pass 1: K-only tiles, 3 buffers -> counted vmcnt(4); pass-2 tile 0
//           prefetched during pass-1's last tile.
//   pass 2: K+V tiles, 2 buffers (parity-flipped); vmcnt(16) leaves the
//           current tile's attn stores in flight.
// ---------------------------------------------------------------------------
#define QBLK 128
#define KB2 128
#define NT2 (SEQ / KB2)
#define C2E 0.18033688f   /* 0.125 * log2(e) */

__global__ __launch_bounds__(256) void flash_attn(
    const u16* __restrict__ Qg, const u16* __restrict__ Kg,
    const u16* __restrict__ Vt, float* __restrict__ attn,
    u16* __restrict__ ctx)
{
    __shared__ u16 smem[32768];
    __shared__ u16 Ps[4][2048];

    const int tid = threadIdx.x;
    const int w = tid >> 6, l = tid & 63;
    const int r16 = l & 15, g = l >> 4;

    const int wg = (blockIdx.x & 7) * (gridDim.x >> 3) + (blockIdx.x >> 3);
    const int qb = wg & 15, z = wg >> 4;
    const int b = z >> 4, h = z & 15;
    const long q0 = (long)qb * QBLK;

    const long kBase = ((long)b * SEQ) * D_MODEL + h * DK;
    const long vBase = (long)z * DK * SEQ;

    u16* const Qs = smem + 24576;       // buf1 V region (dead during init)

#pragma unroll
    for (int r = 0; r < 4; ++r) {
        int c = r * 256 + tid;
        int row = c >> 3, bl = c & 7;
        gload16(Qg + ((long)b * SEQ + q0 + row) * D_MODEL + h * DK + ((bl ^ (row & 7)) * 8),
                Qs + (r * 256 + w * 64) * 8);
    }
#define STAGE_K(dst, kro)                                                     \
    {                                                                         \
        _Pragma("unroll")                                                     \
        for (int r = 0; r < 4; ++r) {                                         \
            int c = r * 256 + tid;                                            \
            int row = c >> 3, bl = c & 7;                                     \
            gload16(Kg + kBase + ((kro) + row) * (long)D_MODEL + ((bl ^ (row & 7)) * 8), \
                    (dst) + (r * 256 + w * 64) * 8);                          \
        }                                                                     \
    }
#define STAGE_V(dst, kro)                                                     \
    {                                                                         \
        _Pragma("unroll")                                                     \
        for (int r = 0; r < 4; ++r) {                                         \
            int c = r * 256 + tid;                                            \
            int row = c >> 4, bl = c & 15;                                    \
            gload16(Vt + vBase + (long)row * SEQ + (kro) + ((bl ^ (row & 15)) * 8), \
                    (dst) + (r * 256 + w * 64) * 8);                          \
        }                                                                     \
    }

    STAGE_K(smem, 0)                    // kb0 = smem+0
    STAGE_K(smem + 16384, KB2)          // kb1 = smem+16384
    __syncthreads();

    bf16x8 qf[2][2];                    // [qi][ks], B-operand in both passes
#pragma unroll
    for (int qi = 0; qi < 2; ++qi)
#pragma unroll
        for (int ks = 0; ks < 2; ++ks)
            qf[qi][ks] = *(const bf16x8*)
                &Qs[(w * 32 + qi * 16 + r16) * 64 + (((ks * 4 + g) ^ (r16 & 7)) * 8)];
    __syncthreads();                    // all waves hoisted; Q region reusable

    // ---------------- pass 1: l = sum exp(s/8)  (3-deep K pipeline) ----------
    float lrun[2] = {0.f, 0.f};

    for (int t = 0; t < NT2; ++t) {
        // kb[i%3]: 0 -> smem+0, 1 -> smem+16384, 2 -> smem+8192 (buf0 V region)
        const int m3n = (t + 2) % 3;
        u16* kdst = (m3n == 0) ? smem : (m3n == 1) ? smem + 16384 : smem + 8192;
        if (t + 2 < NT2) STAGE_K(kdst, (long)(t + 2) * KB2)
        if (t == NT2 - 1) {             // prefetch pass-2 tile 0 (buf1 free)
            STAGE_K(smem + 16384, 0)
            STAGE_V(smem + 24576, 0)
        }
        const int m3c = t % 3;
        const u16* kcur = (m3c == 0) ? smem : (m3c == 1) ? smem + 16384 : smem + 8192;

#pragma unroll
        for (int sub = 0; sub < 2; ++sub) {
            f32x4 sT[4][2];
#pragma unroll
            for (int ki = 0; ki < 4; ++ki)
#pragma unroll
                for (int qi = 0; qi < 2; ++qi) sT[ki][qi] = (f32x4){0.f, 0.f, 0.f, 0.f};

            __builtin_amdgcn_s_setprio(1);
#pragma unroll
            for (int ks = 0; ks < 2; ++ks) {
                bf16x8 kf[4];
#pragma unroll
                for (int ki = 0; ki < 4; ++ki)
                    kf[ki] = *(const bf16x8*)
                        &kcur[(sub * 64 + ki * 16 + r16) * 64 + (((ks * 4 + g) ^ (r16 & 7)) * 8)];
#pragma unroll
                for (int ki = 0; ki < 4; ++ki)
#pragma unroll
                    for (int qi = 0; qi < 2; ++qi)
                        sT[ki][qi] = __builtin_amdgcn_mfma_f32_16x16x32_bf16(
                            kf[ki], qf[qi][ks], sT[ki][qi], 0, 0, 0);
            }
            __builtin_amdgcn_s_setprio(0);

#pragma unroll
            for (int qi = 0; qi < 2; ++qi) {
                float ls = 0.f;
#pragma unroll
                for (int ki = 0; ki < 4; ++ki)
#pragma unroll
                    for (int j = 0; j < 4; ++j)
                        ls += exp2f(sT[ki][qi][j] * C2E);
                ls += __shfl_xor(ls, 16);
                ls += __shfl_xor(ls, 32);
                lrun[qi] += ls;
            }
        }
        if (t + 2 < NT2)      asm volatile("s_waitcnt vmcnt(4)" ::: "memory");
        else if (t + 1 < NT2) asm volatile("s_waitcnt vmcnt(0)" ::: "memory");
        if (t + 1 < NT2) SBAR();
    }

    const float il[2] = {1.0f / lrun[0], 1.0f / lrun[1]};   // q = r16, in-register

    // pass-2 tile 0 was prefetched during pass-1's last tile
    asm volatile("s_waitcnt vmcnt(0)" ::: "memory");
    SBAR();

    // ---------------- pass 2: S^T; plain f32x4 P writes + PV ----------------
    f32x4 acc2[2][4];
#pragma unroll
    for (int mi = 0; mi < 2; ++mi)
#pragma unroll
        for (int ni = 0; ni < 4; ++ni) acc2[mi][ni] = (f32x4){0.f, 0.f, 0.f, 0.f};

    const long arow0 = ((long)z * SEQ + q0 + w * 32) * (long)SEQ;

    for (int t = 0; t < NT2; ++t) {
        const int k0 = t * KB2;
        if (t + 1 < NT2) {
            u16* dst = smem + (t & 1) * 16384;          // parity-flipped
            STAGE_K(dst, (long)(t + 1) * KB2)
            STAGE_V(dst + 8192, (long)(t + 1) * KB2)
        }
        const u16* kcur = smem + (((t + 1) & 1)) * 16384;
        const u16* vcur = kcur + 8192;

#pragma unroll
        for (int sub = 0; sub < 2; ++sub) {
            f32x4 sT[4][2];
#pragma unroll
            for (int ki = 0; ki < 4; ++ki)
#pragma unroll
                for (int qi = 0; qi < 2; ++qi) sT[ki][qi] = (f32x4){0.f, 0.f, 0.f, 0.f};

            __builtin_amdgcn_s_setprio(1);
#pragma unroll
            for (int ks = 0; ks < 2; ++ks) {
                bf16x8 kf[4];
#pragma unroll
                for (int ki = 0; ki < 4; ++ki)
                    kf[ki] = *(const bf16x8*)
                        &kcur[(sub * 64 + ki * 16 + r16) * 64 + (((ks * 4 + g) ^ (r16 & 7)) * 8)];
#pragma unroll
                for (int ki = 0; ki < 4; ++ki)
#pragma unroll
                    for (int qi = 0; qi < 2; ++qi)
                        sT[ki][qi] = __builtin_amdgcn_mfma_f32_16x16x32_bf16(
                            kf[ki], qf[qi][ks], sT[ki][qi], 0, 0, 0);
            }
            __builtin_amdgcn_s_setprio(0);

#pragma unroll
            for (int qi = 0; qi < 2; ++qi) {
                const long ar = arow0 + (long)(qi * 16 + r16) * SEQ + k0 + sub * 64 + g * 4;
                const int prow = (qi * 16 + r16) * 64;
#pragma unroll
                for (int ki = 0; ki < 4; ++ki) {
                    f32x4 p;
                    p[0] = exp2f(sT[ki][qi][0] * C2E) * il[qi];
                    p[1] = exp2f(sT[ki][qi][1] * C2E) * il[qi];
                    p[2] = exp2f(sT[ki][qi][2] * C2E) * il[qi];
                    p[3] = exp2f(sT[ki][qi][3] * C2E) * il[qi];
                    *(f32x4*)&attn[ar + ki * 16] = p;           // plain cached store
                    us4 pb;
                    pb[0] = f2b(p[0]); pb[1] = f2b(p[1]);
                    pb[2] = f2b(p[2]); pb[3] = f2b(p[3]);
                    const int kblk = 2 * ki + (g >> 1);
                    *(us4*)&Ps[w][prow + ((kblk ^ (r16 & 7)) << 3) + ((g & 1) << 2)] = pb;
                }
            }

            __builtin_amdgcn_s_setprio(1);
#pragma unroll
            for (int ks = 0; ks < 2; ++ks) {
                bf16x8 pf[2], vf[4];
#pragma unroll
                for (int mi = 0; mi < 2; ++mi)
                    pf[mi] = *(const bf16x8*)
                        &Ps[w][(mi * 16 + r16) * 64 + (((ks * 4 + g) ^ (r16 & 7)) << 3)];
#pragma unroll
                for (int ni = 0; ni < 4; ++ni) {
                    const int row = ni * 16 + r16;
                    const int slot = sub * 8 + ks * 4 + g;
                    vf[ni] = *(const bf16x8*)
                        &vcur[row * 128 + ((slot ^ (row & 15)) * 8)];
                }
#pragma unroll
                for (int mi = 0; mi < 2; ++mi)
#pragma unroll
                    for (int ni = 0; ni < 4; ++ni)
                        acc2[mi][ni] = __builtin_amdgcn_mfma_f32_16x16x32_bf16(
                            pf[mi], vf[ni], acc2[mi][ni], 0, 0, 0);
            }
            __builtin_amdgcn_s_setprio(0);
        }

        if (t + 1 < NT2) {
            asm volatile("s_waitcnt vmcnt(16)" ::: "memory");
            SBAR();
        }
    }
#undef STAGE_K
#undef STAGE_V

    // ---- ctx epilogue (bf16); C layout: row=q=g*4+j(+16mi), col=d=ni*16+r16
#pragma unroll
    for (int mi = 0; mi < 2; ++mi)
#pragma unroll
        for (int j = 0; j < 4; ++j) {
            const long grow = (long)b * SEQ + q0 + w * 32 + mi * 16 + g * 4 + j;
#pragma unroll
            for (int ni = 0; ni < 4; ++ni)
                ctx[grow * D_MODEL + h * DK + ni * 16 + r16] = f2b(acc2[mi][ni][j]);
        }
}

// ---------------------------------------------------------------------------
// Merged preprocessing: x cvt + 4x square-W transpose + W1/W2 transpose.
// All f32 sources are single-touch -> non-temporal loads.
// ---------------------------------------------------------------------------
__device__ __forceinline__ void tr32(
    const float* __restrict__ W, u16* __restrict__ Wt, int R, int C,
    int bx, int by, int tx, int ty, float (*t)[33])
{
    const long c = (long)bx * 32 + tx;
    const long r0 = (long)by * 32;
#pragma unroll
    for (int j = 0; j < 32; j += 8)
        t[ty + j][tx] = __builtin_nontemporal_load(&W[(r0 + ty + j) * C + c]);
    __syncthreads();
    const long r = r0 + tx;
#pragma unroll
    for (int j = 0; j < 32; j += 8)
        Wt[((long)bx * 32 + ty + j) * R + r] = f2b(t[tx][ty + j]);
}

__global__ __launch_bounds__(256) void preproc(
    const float* __restrict__ x, u16* __restrict__ x_bf,
    const float* __restrict__ Wq, const float* __restrict__ Wk,
    const float* __restrict__ Wv, const float* __restrict__ Wo,
    u16* __restrict__ Wqkvo_t,
    const float* __restrict__ W1, u16* __restrict__ W1t,
    const float* __restrict__ W2, u16* __restrict__ W2t)
{
    __shared__ float t[32][33];
    int bid = blockIdx.x;
    const int tx = threadIdx.x & 31, ty = threadIdx.x >> 5;

    if (bid < 2048) {
        long i = ((long)bid * 256 + threadIdx.x) * 8;
        f32x4 a = __builtin_nontemporal_load((const f32x4*)(x + i));
        f32x4 b = __builtin_nontemporal_load((const f32x4*)(x + i + 4));
        us8 o;
        o[0] = f2b(a[0]); o[1] = f2b(a[1]); o[2] = f2b(a[2]); o[3] = f2b(a[3]);
        o[4] = f2b(b[0]); o[5] = f2b(b[1]); o[6] = f2b(b[2]); o[7] = f2b(b[3]);
        *(us8*)(x_bf + i) = o;
        return;
    }
    bid -= 2048;
    if (bid < 4096) {
        const int z = bid >> 10, rem = bid & 1023;
        const float* W = (z == 0) ? Wq : (z == 1) ? Wk : (z == 2) ? Wv : Wo;
        tr32(W, Wqkvo_t + (size_t)z * D_MODEL * D_MODEL, D_MODEL, D_MODEL,
             rem & 31, rem >> 5, tx, ty, t);
        return;
    }
    bid -= 4096;
    if (bid < 4096) {
        tr32(W1, W1t, D_MODEL, D_FF, bid & 127, bid >> 7, tx, ty, t);
        return;
    }
    bid -= 4096;
    {
        tr32(W2, W2t, D_FF, D_MODEL, bid & 31, bid >> 5, tx, ty, t);
    }
}

// ---------------------------------------------------------------------------
// V_bf [b*2048+k][1024] -> Vt [(b*16+h)*64+d][2048]   (per-head transpose)
// ---------------------------------------------------------------------------
__global__ __launch_bounds__(256) void transpose_v(
    const u16* __restrict__ V, u16* __restrict__ Vt)
{
    __shared__ u16 t[32][33];
    const int z = blockIdx.z, b = z >> 4, h = z & 15;
    const int tx = threadIdx.x & 31, ty = threadIdx.x >> 5;
    const long k0 = (long)blockIdx.x * 32;
    const long d0 = (long)blockIdx.y * 32;
#pragma unroll
    for (int j = 0; j < 32; j += 8)
        t[ty + j][tx] = V[((long)b * SEQ + k0 + ty + j) * D_MODEL + h * DK + d0 + tx];
    __syncthreads();
#pragma unroll
    for (int j = 0; j < 32; j += 8)
        Vt[((long)z * DK + d0 + ty + j) * SEQ + k0 + tx] = t[tx][ty + j];
}

// ---------------------------------------------------------------------------
// out = LayerNorm(a_bf + b_bf) * g + be ; one wave per row.
//   OM: 0 = f32 out, 1 = bf16 out.
// ---------------------------------------------------------------------------
template<int OM>
__global__ __launch_bounds__(256) void add_ln_kernel(
    const u16* __restrict__ a, const u16* __restrict__ b,
    const float* __restrict__ g, const float* __restrict__ be,
    void* __restrict__ outp)
{
    const int l = threadIdx.x & 63, w = threadIdx.x >> 6;
    const long row = (long)blockIdx.x * 4 + w;
    const long base = row * D_MODEL;

    float xv[16];
#pragma unroll
    for (int c = 0; c < 2; ++c) {
        const long off = c * 512 + l * 8;
        us8 av = *(const us8*)(a + base + off);
        us8 bv = *(const us8*)(b + base + off);
#pragma unroll
        for (int i = 0; i < 8; ++i)
            xv[c * 8 + i] = b2f(av[i]) + b2f(bv[i]);
    }

    float s = 0.f;
#pragma unroll
    for (int i = 0; i < 16; ++i) s += xv[i];
#pragma unroll
    for (int off = 1; off < 64; off <<= 1) s += __shfl_xor(s, off);
    const float mean = s * (1.0f / D_MODEL);

    float ss = 0.f;
#pragma unroll
    for (int i = 0; i < 16; ++i) {
        xv[i] -= mean;
        ss += xv[i] * xv[i];
    }
#pragma unroll
    for (int off = 1; off < 64; off <<= 1) ss += __shfl_xor(ss, off);
    const float rs = rsqrtf(ss * (1.0f / D_MODEL) + EPS);

#pragma unroll
    for (int c = 0; c < 2; ++c) {
        const long off = c * 512 + l * 8;
        float4 g0 = *(const float4*)(g + off);
        float4 g1 = *(const float4*)(g + off + 4);
        float4 b0 = *(const float4*)(be + off);
        float4 b1 = *(const float4*)(be + off + 4);
        float o[8];
        o[0] = xv[c*8+0] * rs * g0.x + b0.x;
        o[1] = xv[c*8+1] * rs * g0.y + b0.y;
        o[2] = xv[c*8+2] * rs * g0.z + b0.z;
        o[3] = xv[c*8+3] * rs * g0.w + b0.w;
        o[4] = xv[c*8+4] * rs * g1.x + b1.x;
        o[5] = xv[c*8+5] * rs * g1.y + b1.y;
        o[6] = xv[c*8+6] * rs * g1.z + b1.z;
        o[7] = xv[c*8+7] * rs * g1.w + b1.w;
        if (OM == 0) {
            float4 v0 = {o[0], o[1], o[2], o[3]};
            float4 v1 = {o[4], o[5], o[6], o[7]};
            *(float4*)((float*)outp + base + off) = v0;
            *(float4*)((float*)outp + base + off + 4) = v1;
        } else {
            us8 ob;
#pragma unroll
            for (int i = 0; i < 8; ++i) ob[i] = f2b(o[i]);
            *(us8*)((u16*)outp + base + off) = ob;
        }
    }
}

// ---------------------------------------------------------------------------
extern "C" void kernel_launch(void* const* d_in, const int* in_sizes, int n_in,
                              void* d_out, int out_size, void* d_ws, size_t ws_size,
                              hipStream_t stream)
{
    const float* x   = (const float*)d_in[0];
    const float* Wq  = (const float*)d_in[1];
    const float* bq  = (const float*)d_in[2];
    const float* Wk  = (const float*)d_in[3];
    const float* bk  = (const float*)d_in[4];
    const float* Wv  = (const float*)d_in[5];
    const float* bv  = (const float*)d_in[6];
    const float* Wo  = (const float*)d_in[7];
    const float* bo  = (const float*)d_in[8];
    const float* W1  = (const float*)d_in[9];
    const float* b1  = (const float*)d_in[10];
    const float* W2  = (const float*)d_in[11];
    const float* b2  = (const float*)d_in[12];
    const float* g1  = (const float*)d_in[13];
    const float* be1 = (const float*)d_in[14];
    const float* g2  = (const float*)d_in[15];
    const float* be2 = (const float*)d_in[16];

    float* out  = (float*)d_out;
    float* attn = out + (size_t)BATCH * SEQ * D_MODEL;

    char* ws = (char*)d_ws;
    const size_t MB = 1u << 20;
    u16* x_bf    = (u16*)(ws);              // 0-8 MB   (live until LN1)
    u16* Q_bf    = (u16*)(ws + 8 * MB);     // 8-16
    u16* K_bf    = (u16*)(ws + 16 * MB);    // 16-24    (then h_bf)
    u16* Vt      = (u16*)(ws + 24 * MB);    // 24-32    (then ff2_bf)
    u16* V_bf    = (u16*)(ws + 32 * MB);    // 32-40    (then ao_bf)
    u16* Wqkvo_t = (u16*)(ws + 40 * MB);    // 40-48
    u16* W1t     = (u16*)(ws + 48 * MB);    // 48-56
    u16* W2t     = (u16*)(ws + 56 * MB);    // 56-64
    u16* ff1_bf  = (u16*)(ws + 64 * MB);    // 64-96
    u16* ctx_bf  = (u16*)(ws + 96 * MB);    // 96-104
    u16* Wot     = Wqkvo_t + (size_t)3 * D_MODEL * D_MODEL;
    u16* h_bf    = K_bf;                    // K dead after flash_attn
    u16* ao_bf   = V_bf;                    // V_bf dead after transpose_v
    u16* ff2_bf  = Vt;                      // Vt dead after flash_attn

    const int M = BATCH * SEQ;              // 4096
    dim3 T(256);

    preproc<<<dim3(2048 + 3 * 4096), T, 0, stream>>>(
        x, x_bf, Wq, Wk, Wv, Wo, Wqkvo_t, W1, W1t, W2, W2t);

    // --- fused QKV projection: N=3072, BK=32 / 3 blocks/CU (R17 config) ---
    gemm_mfma<false, 3><<<dim3((M / 128) * 24), T, 0, stream>>>(
        x_bf, Wqkvo_t, bq, bk, bv, Q_bf, K_bf, V_bf,
        D_MODEL, D_MODEL, D_MODEL, D_MODEL, 24);

    transpose_v<<<dim3(SEQ / 32, DK / 32, BATCH * NUM_HEADS), T, 0, stream>>>(V_bf, Vt);

    flash_attn<<<dim3((SEQ / QBLK) * BATCH * NUM_HEADS), T, 0, stream>>>(
        Q_bf, K_bf, Vt, attn, ctx_bf);

    // --- Wo projection (bf16 out; 128x128/BK=64, 256 blocks x 8 waves) ---
    gemm_w2<false><<<dim3((M / 128) * 8), dim3(512), 0, stream>>>(
        ctx_bf, Wot, bo, ao_bf, D_MODEL, D_MODEL, D_MODEL, D_MODEL, 8);

    add_ln_kernel<1><<<dim3(M / 4), T, 0, stream>>>(x_bf, ao_bf, g1, be1, h_bf);

    // --- FF1 (256² 4-phase, 256 blocks x 8 waves) ---
    gemm256<D_MODEL, true><<<dim3((M / 256) * (D_FF / 256)), dim3(512), 0, stream>>>(
        h_bf, W1t, b1, ff1_bf, D_FF, D_FF / 256);

    // --- FF2 (bf16 out; 128x128/BK=64, 256 blocks x 8 waves) ---
    gemm_w2<false><<<dim3((M / 128) * 8), dim3(512), 0, stream>>>(
        ff1_bf, W2t, b2, ff2_bf, D_FF, D_FF, D_MODEL, D_FF, 8);

    add_ln_kernel<0><<<dim3(M / 4), T, 0, stream>>>(h_bf, ff2_bf, g2, be2, out);
}